// Round 7
// baseline (18852.208 us; speedup 1.0000x reference)
//
#include <hip/hip_runtime.h>
#include <cmath>

constexpr int kB = 64, kS = 512, kD = 128, kH = 512, kOut = 24;
constexpr int kBlocks = 256, kThreads = 512;   // grid<=256: proven coop-launchable
constexpr size_t kBarOffBytes = (size_t)5 * kB * kH * 4;   // after H0,H1,tmp1

struct Params {
  const float* x;
  const float* w0[4]; const float* b0[4];   // f,i,o,g  [512,640] / [512]
  const float* w1[4]; const float* b1[4];   // f,i,o,g  [512,1024] / [512]
  const float* fc1w; const float* fc1b;
  const float* fc2w; const float* fc2b;
  float* H0;    // 2 buffers [64][512]
  float* H1;    // 2 buffers [64][512]
  float* tmp1;  // [64][512]
  unsigned* bar; // per-group: slots g @ g*512 (32 x 16 words), gen @ 4096+g*16
  float* out;   // [64][24]
};

__device__ __forceinline__ float sigmoidf_(float v) {
  return 1.0f / (1.0f + expf(-v));
}

// Store-based group barrier (parallel slot stores, no RMW serialization;
// round-4 verified). Leader polls n slots with n lanes + __syncthreads_and.
// Monotone counters. With n=32 and all members on ONE XCD (bid%8 grouping,
// learn_hip m157 dispatch model), all traffic is XCD-L2-local -> ~0.5us.
// Correct for ANY placement (agent scope); placement only affects speed.
__device__ __forceinline__ void sync_group(unsigned* slots, unsigned* gen,
                                           int myIdx, int n, bool leader,
                                           unsigned r) {
  const int tid = threadIdx.x;
  __syncthreads();
  if (leader) {
    if (tid == 0) {
      __threadfence();
      __hip_atomic_store(slots + myIdx * 16, r + 1, __ATOMIC_RELAXED,
                         __HIP_MEMORY_SCOPE_AGENT);
    }
    unsigned* ps = slots + (tid < n ? tid : 0) * 16;
    for (;;) {
      unsigned v = __hip_atomic_load(ps, __ATOMIC_RELAXED,
                                     __HIP_MEMORY_SCOPE_AGENT);
      if (__syncthreads_and((tid < n) ? (int)(v > r) : 1)) break;
      __builtin_amdgcn_s_sleep(1);
    }
    __threadfence();
    if (tid == 0)
      __hip_atomic_store(gen, r + 1, __ATOMIC_RELAXED,
                         __HIP_MEMORY_SCOPE_AGENT);
    __syncthreads();
  } else {
    if (tid == 0) {
      __threadfence();
      __hip_atomic_store(slots + myIdx * 16, r + 1, __ATOMIC_RELAXED,
                         __HIP_MEMORY_SCOPE_AGENT);
      while (__hip_atomic_load(gen, __ATOMIC_RELAXED,
                               __HIP_MEMORY_SCOPE_AGENT) <= r)
        __builtin_amdgcn_s_sleep(1);
      __threadfence();
    }
    __syncthreads();
  }
}

// ROUND-7 ARCHITECTURE SWITCH (rounds 4/5/6 evidence: the hidden-split design
// is pinned ~28us/step by 128-block cross-XCD sync + h broadcast to 128
// readers through L3; no incremental edit moved it):
//   The LSTM recurrence is independent PER BATCH. Group g = bid&7 owns
//   batches 8g..8g+7; its 32 blocks (all with bid%8==g -> same XCD under
//   round-robin dispatch) cover col-slices s=bid>>3 (16 cols x 4 gates each).
//   - sync group = 32 XCD-local blocks, 1 barrier/step
//   - h read by 32 same-XCD blocks only -> L2-local (was 128 readers via L3)
//   - thread (r,b) computes ONE gate preact with FULL K -> no reductions,
//     no k-loop barriers; u (8 batches) staged ONCE per phase (2 syncs/phase)
//   - weights: layer0 k in [128,608) LDS-resident (loaded once, 124KB);
//     the rest (layer0 x-part+tail, all layer1, ~300KB/block) streams from
//     L3 each step; 8 batch-lanes share each W address -> coalesced requests,
//     float4-sequential per row -> full cache-line use.
__global__ void __launch_bounds__(kThreads, 2)
lstm_persistent(Params p) {
  __shared__ float wlds[64 * 484];     // 123.9KB: layer0 W rows, k in [128,608)
  __shared__ float u[8 * 1036];        // 33.2KB: u stage, stride 1036 (bank-spread)
  __shared__ float gs[64 * 8];         // 2KB: gate preacts [r][b]

  const int tid = threadIdx.x;
  const int bid = blockIdx.x;
  const int g  = bid & 7;              // batch octet (XCD-local)
  const int s  = bid >> 3;             // col-slice 0..31
  const int j0 = s * 16;
  const int b0 = g * 8;

  // compute mapping: thread = (gate-row r, batch bt)
  const int r  = tid >> 3;             // 0..63: gate gi=r>>4, col jl=r&15
  const int bt = tid & 7;
  const int gi = r >> 4;
  const int jl = r & 15;

  const float* __restrict__ w0row = p.w0[gi] + (j0 + jl) * 640;
  const float* __restrict__ w1row = p.w1[gi] + (j0 + jl) * 1024;

  // one-time: layer0 W bulk -> LDS (64 rows x 120 f4, k floats 128..607)
  for (int i = tid; i < 64 * 120; i += kThreads) {
    const int rr = i / 120, q = i - rr * 120;
    *(float4*)(&wlds[rr * 484 + q * 4]) =
        *(const float4*)(p.w0[rr >> 4] + (j0 + (rr & 15)) * 640 + 128 + q * 4);
  }

  // zero-init prev buffers (index 1) for our (batches, col-slice)
  if (tid < 128) {
    const int jj = tid >> 3, bb = tid & 7;
    p.H0[kB * kH + (b0 + bb) * kH + j0 + jj] = 0.f;
    p.H1[kB * kH + (b0 + bb) * kH + j0 + jj] = 0.f;
  }

  float* H0buf[2] = { p.H0, p.H0 + kB * kH };
  float* H1buf[2] = { p.H1, p.H1 + kB * kH };
  float c0 = 0.f, c1 = 0.f;

  unsigned* gSlots = p.bar + g * 512;
  unsigned* gGen   = p.bar + 4096 + g * 16;
  const bool leader = (s == 0);
  unsigned rnd = 0;

  sync_group(gSlots, gGen, s, 32, leader, rnd); rnd++;   // zeros visible

  // ---------- layer 0: u = [x_t(128) | h0prev(512)], K=640 ----------
  auto phaseA = [&](int t, const float* __restrict__ h0prev,
                    float* __restrict__ h0out) {
    for (int i = tid; i < 1024; i += kThreads) {      // k floats 0..511
      const int bb = i >> 7, q = i & 127;
      const float4 v = (q < 32)
          ? *(const float4*)(p.x + ((b0 + bb) * kS + t) * kD + q * 4)
          : *(const float4*)(h0prev + (b0 + bb) * kH + (q - 32) * 4);
      *(float4*)(&u[bb * 1036 + q * 4]) = v;
    }
    if (tid < 256) {                                   // k floats 512..639
      const int bb = tid >> 5, q = tid & 31;
      *(float4*)(&u[bb * 1036 + 512 + q * 4]) =
          *(const float4*)(h0prev + (b0 + bb) * kH + 384 + q * 4);
    }
    __syncthreads();

    const float* __restrict__ ub = &u[bt * 1036];
    const float* __restrict__ wl = &wlds[r * 484];
    float4 a = { 0.f, 0.f, 0.f, 0.f };
    #pragma unroll 8
    for (int q = 0; q < 32; ++q) {                    // x part: global W
      const float4 w = *(const float4*)(w0row + q * 4);
      const float4 uu = *(const float4*)(ub + q * 4);
      a.x = fmaf(w.x, uu.x, a.x); a.y = fmaf(w.y, uu.y, a.y);
      a.z = fmaf(w.z, uu.z, a.z); a.w = fmaf(w.w, uu.w, a.w);
    }
    #pragma unroll 8
    for (int q = 0; q < 120; ++q) {                   // bulk: LDS W (bcast)
      const float4 w = *(const float4*)(wl + q * 4);
      const float4 uu = *(const float4*)(ub + 128 + q * 4);
      a.x = fmaf(w.x, uu.x, a.x); a.y = fmaf(w.y, uu.y, a.y);
      a.z = fmaf(w.z, uu.z, a.z); a.w = fmaf(w.w, uu.w, a.w);
    }
    #pragma unroll
    for (int q = 152; q < 160; ++q) {                 // tail: global W
      const float4 w = *(const float4*)(w0row + q * 4);
      const float4 uu = *(const float4*)(ub + q * 4);
      a.x = fmaf(w.x, uu.x, a.x); a.y = fmaf(w.y, uu.y, a.y);
      a.z = fmaf(w.z, uu.z, a.z); a.w = fmaf(w.w, uu.w, a.w);
    }
    gs[r * 8 + bt] = (a.x + a.y) + (a.z + a.w) + p.b0[gi][j0 + jl];
    __syncthreads();
    if (tid < 128) {
      const int jj = tid >> 3, bb = tid & 7;
      const float fg = sigmoidf_(gs[(0 * 16 + jj) * 8 + bb]);
      const float ig = sigmoidf_(gs[(1 * 16 + jj) * 8 + bb]);
      const float og = sigmoidf_(gs[(2 * 16 + jj) * 8 + bb]);
      const float gg = tanhf(gs[(3 * 16 + jj) * 8 + bb]);
      c0 = fg * c0 + ig * gg;
      h0out[(b0 + bb) * kH + j0 + jj] = og * tanhf(c0);
    }
    // u overwrite by next phase is safe: all k-loop reads precede the gs
    // sync; gs readers write only global h. Next phase's post-stage sync
    // orders everything.
  };

  // ---------- layer 1: u = [h0cur(512) | h1prev(512)], K=1024 ----------
  auto phaseB = [&](const float* __restrict__ h0cur,
                    const float* __restrict__ h1prev,
                    float* __restrict__ h1out) {
    for (int i = tid; i < 2048; i += kThreads) {
      const int bb = i >> 8, q = i & 255;
      const float4 v = (q < 128)
          ? *(const float4*)(h0cur + (b0 + bb) * kH + q * 4)
          : *(const float4*)(h1prev + (b0 + bb) * kH + (q - 128) * 4);
      *(float4*)(&u[bb * 1036 + q * 4]) = v;
    }
    __syncthreads();

    const float* __restrict__ ub = &u[bt * 1036];
    float4 a = { 0.f, 0.f, 0.f, 0.f };
    #pragma unroll 8
    for (int q = 0; q < 256; ++q) {                   // all-global W stream
      const float4 w = *(const float4*)(w1row + q * 4);
      const float4 uu = *(const float4*)(ub + q * 4);
      a.x = fmaf(w.x, uu.x, a.x); a.y = fmaf(w.y, uu.y, a.y);
      a.z = fmaf(w.z, uu.z, a.z); a.w = fmaf(w.w, uu.w, a.w);
    }
    gs[r * 8 + bt] = (a.x + a.y) + (a.z + a.w) + p.b1[gi][j0 + jl];
    __syncthreads();
    if (tid < 128) {
      const int jj = tid >> 3, bb = tid & 7;
      const float fg = sigmoidf_(gs[(0 * 16 + jj) * 8 + bb]);
      const float ig = sigmoidf_(gs[(1 * 16 + jj) * 8 + bb]);
      const float og = sigmoidf_(gs[(2 * 16 + jj) * 8 + bb]);
      const float gg = tanhf(gs[(3 * 16 + jj) * 8 + bb]);
      c1 = fg * c1 + ig * gg;
      h1out[(b0 + bb) * kH + j0 + jj] = og * tanhf(c1);
    }
  };

  // ---------- sequence: 1 XCD-local group barrier per step ----------
  phaseA(0, H0buf[1], H0buf[0]);
  sync_group(gSlots, gGen, s, 32, leader, rnd); rnd++;

  for (int t = 0; t < kS; ++t) {
    phaseB(H0buf[t & 1], H1buf[(t + 1) & 1], H1buf[t & 1]);
    if (t < kS - 1)
      phaseA(t + 1, H0buf[t & 1], H0buf[(t + 1) & 1]);
    sync_group(gSlots, gGen, s, 32, leader, rnd); rnd++;
  }

  // ---------- head: fc1 -> (group barrier) -> fc2 -> relu ----------
  const float* h1f = H1buf[(kS - 1) & 1];
  if (tid < 128) {
    const int jj = tid >> 3, bb = tid & 7;
    const float* __restrict__ wr = p.fc1w + (j0 + jj) * kH;
    const float* __restrict__ hr = h1f + (b0 + bb) * kH;
    float4 a = { 0.f, 0.f, 0.f, 0.f };
    for (int k = 0; k < kH; k += 4) {
      const float4 wv = *(const float4*)(wr + k);
      const float4 hv = *(const float4*)(hr + k);
      a.x = fmaf(wv.x, hv.x, a.x); a.y = fmaf(wv.y, hv.y, a.y);
      a.z = fmaf(wv.z, hv.z, a.z); a.w = fmaf(wv.w, hv.w, a.w);
    }
    p.tmp1[(b0 + bb) * kH + j0 + jj] =
        (a.x + a.y) + (a.z + a.w) + p.fc1b[j0 + jj];
  }
  sync_group(gSlots, gGen, s, 32, leader, rnd); rnd++;

  if (s == 0 && tid < 192) {                          // 8 batches x 24 outs
    const int bb = tid / 24, o = tid - bb * 24;
    const float* __restrict__ wr = p.fc2w + o * kH;
    const float* __restrict__ tr = p.tmp1 + (b0 + bb) * kH;
    float4 a = { 0.f, 0.f, 0.f, 0.f };
    for (int k = 0; k < kH; k += 4) {
      const float4 wv = *(const float4*)(wr + k);
      const float4 tv = *(const float4*)(tr + k);
      a.x = fmaf(wv.x, tv.x, a.x); a.y = fmaf(wv.y, tv.y, a.y);
      a.z = fmaf(wv.z, tv.z, a.z); a.w = fmaf(wv.w, tv.w, a.w);
    }
    const float sv = (a.x + a.y) + (a.z + a.w) + p.fc2b[o];
    p.out[(b0 + bb) * kOut + o] = fmaxf(sv, 0.f);
  }
}

extern "C" void kernel_launch(void* const* d_in, const int* in_sizes, int n_in,
                              void* d_out, int out_size, void* d_ws, size_t ws_size,
                              hipStream_t stream) {
  (void)in_sizes; (void)n_in; (void)out_size; (void)ws_size;
  Params p;
  p.x = (const float*)d_in[0];
  p.w0[0] = (const float*)d_in[1];  p.b0[0] = (const float*)d_in[2];
  p.w0[1] = (const float*)d_in[3];  p.b0[1] = (const float*)d_in[4];
  p.w0[2] = (const float*)d_in[5];  p.b0[2] = (const float*)d_in[6];
  p.w0[3] = (const float*)d_in[7];  p.b0[3] = (const float*)d_in[8];
  p.w1[0] = (const float*)d_in[9];  p.b1[0] = (const float*)d_in[10];
  p.w1[1] = (const float*)d_in[11]; p.b1[1] = (const float*)d_in[12];
  p.w1[2] = (const float*)d_in[13]; p.b1[2] = (const float*)d_in[14];
  p.w1[3] = (const float*)d_in[15]; p.b1[3] = (const float*)d_in[16];
  p.fc1w = (const float*)d_in[17];  p.fc1b = (const float*)d_in[18];
  p.fc2w = (const float*)d_in[19];  p.fc2b = (const float*)d_in[20];

  float* ws = (float*)d_ws;
  p.H0   = ws;                       // 2 * 64*512
  p.H1   = ws + 2 * kB * kH;         // 2 * 64*512
  p.tmp1 = ws + 4 * kB * kH;         // 64*512
  p.bar  = (unsigned*)((char*)d_ws + kBarOffBytes);
  p.out  = (float*)d_out;

  // barrier state must start at 0 (ws is poisoned 0xAA before every launch)
  // region: 8 groups x 512 slot-words + gens = 4224 words -> clear 20KB
  hipMemsetAsync((char*)d_ws + kBarOffBytes, 0, 20480, stream);

  void* args[] = { &p };
  hipLaunchCooperativeKernel(reinterpret_cast<const void*>(&lstm_persistent),
                             dim3(kBlocks), dim3(kThreads), args, 0, stream);
}

// Round 9
// 14889.758 us; speedup vs baseline: 1.2661x; 1.2661x over previous
//
#include <hip/hip_runtime.h>
#include <cmath>

constexpr int kB = 64, kS = 512, kD = 128, kH = 512, kOut = 24;
constexpr int kBlocks = 256, kThreads = 512;   // grid<=256: proven coop-launchable
constexpr size_t kBarOffBytes = (size_t)5 * kB * kH * 4;   // after H0,H1,tmp1

struct Params {
  const float* x;
  const float* w0[4]; const float* b0[4];   // f,i,o,g  [512,640] / [512]
  const float* w1[4]; const float* b1[4];   // f,i,o,g  [512,1024] / [512]
  const float* fc1w; const float* fc1b;
  const float* fc2w; const float* fc2b;
  float* H0;    // 2 buffers [64][512]
  float* H1;    // 2 buffers [64][512]
  float* tmp1;  // [64][512]
  unsigned* bar; // word layout: dom slots [0,4096), dom gen @4096+d*16,
                 //              full slots [4224,8320), full gen @8320
  float* out;   // [64][24]
};

__device__ __forceinline__ float sigmoidf_(float v) {
  return 1.0f / (1.0f + expf(-v));
}

// Store-based group barrier (parallel slot stores, no RMW serialization;
// round-4 verified). Leader polls n slots with n lanes + __syncthreads_and.
__device__ __forceinline__ void sync_group(unsigned* slots, unsigned* gen,
                                           int myIdx, int n, bool leader,
                                           unsigned r) {
  const int tid = threadIdx.x;
  __syncthreads();
  if (leader) {
    if (tid == 0) {
      __threadfence();
      __hip_atomic_store(slots + myIdx * 16, r + 1, __ATOMIC_RELAXED,
                         __HIP_MEMORY_SCOPE_AGENT);
    }
    unsigned* ps = slots + (tid < n ? tid : 0) * 16;
    for (;;) {
      unsigned v = __hip_atomic_load(ps, __ATOMIC_RELAXED,
                                     __HIP_MEMORY_SCOPE_AGENT);
      if (__syncthreads_and((tid < n) ? (int)(v > r) : 1)) break;
      __builtin_amdgcn_s_sleep(1);
    }
    __threadfence();
    if (tid == 0)
      __hip_atomic_store(gen, r + 1, __ATOMIC_RELAXED,
                         __HIP_MEMORY_SCOPE_AGENT);
    __syncthreads();
  } else {
    if (tid == 0) {
      __threadfence();
      __hip_atomic_store(slots + myIdx * 16, r + 1, __ATOMIC_RELAXED,
                         __HIP_MEMORY_SCOPE_AGENT);
      while (__hip_atomic_load(gen, __ATOMIC_RELAXED,
                               __HIP_MEMORY_SCOPE_AGENT) <= r)
        __builtin_amdgcn_s_sleep(1);
      __threadfence();
    }
    __syncthreads();
  }
}

// ROUND-9: round-8 architecture with the suspect removed.
// Round-8 failed correctness (5.1e-3); the only source-level-unverifiable
// component was the barrier-free cross-lane LDS u hand-off (C++ data race,
// relied on wave-lockstep + DS in-order). Fix: u NEVER touches LDS.
//   Thread (kt=l&15, bi=l>>4) owns batch bme = bbase + wv*4 + bi and k-slice
//   [8kt, 8kt+8) of every 128-float chunk. It loads those 8 floats DIRECTLY
//   from global into registers: 2 dwordx4, perfectly coalesced within the
//   bi-group (16 lanes x 32B contiguous), prefetched 2 chunks ahead.
//   The k-loop touches NO shared state except read-only W in LDS (one-time
//   init, fenced by the first group barrier). Cross-thread comms = shfl
//   butterfly (exact) + barrier-fenced global h (rounds 0-7 proven).
//   Per step: 0 block syncs + 1 domain barrier.
// This bench also answers an open HW question: W LDS reads are 4-way
// same-address broadcast across bi lanes. If broadcast is return-path-free,
// W traffic is 852KB/step/block (~4us); if not, 3.4MB (~17us) -> fork.
__global__ void __launch_bounds__(kThreads, 2)
lstm_persistent(Params p) {
  __shared__ float wlds0[16 * 644];    // 41.2 KB  w0 slice (row stride 644)
  __shared__ float wlds1[16 * 1028];   // 65.8 KB  w1 slice (row stride 1028)
  __shared__ float blds[32];           // biases [layer][16 rows]

  const int tid = threadIdx.x;
  const int bid = blockIdx.x;
  const int cgi = bid >> 1;
  const int bh  = bid & 1;
  const int j0  = cgi * 4;
  const int bbase = bh * 32;

  const int wv = tid >> 6;
  const int l  = tid & 63;
  const int kt = l & 15;               // k-slice (16-way): floats [8kt,8kt+8)
  const int bi = l >> 4;               // wave-local batch 0..3
  const int bme = bbase + wv * 4 + bi; // this thread's batch

  // one-time: W slices -> LDS (row r = gate*4 + col, padded strides)
  for (int idx = tid; idx < 16 * 160; idx += kThreads) {   // w0: 16 x 160 f4
    const int row = idx / 160;
    const int k4  = idx - row * 160;
    *(float4*)(wlds0 + row * 644 + k4 * 4) =
        *(const float4*)(p.w0[row >> 2] + (j0 + (row & 3)) * 640 + k4 * 4);
  }
  for (int idx = tid; idx < 16 * 256; idx += kThreads) {   // w1: 16 x 256 f4
    const int row = idx >> 8;
    const int k4  = idx & 255;
    *(float4*)(wlds1 + row * 1028 + k4 * 4) =
        *(const float4*)(p.w1[row >> 2] + (j0 + (row & 3)) * 1024 + k4 * 4);
  }
  if (tid < 16)       blds[tid] = p.b0[tid >> 2][j0 + (tid & 3)];
  else if (tid < 32)  blds[tid] = p.b1[(tid - 16) >> 2][j0 + (tid & 3)];

  // zero-init buffers read at t=0 (buffer index 1)
  if (tid < 128) {
    const int jl = tid >> 5, bb = tid & 31;
    const int b = bbase + bb;
    p.H0[kB * kH + b * kH + j0 + jl] = 0.f;
    p.H1[kB * kH + b * kH + j0 + jl] = 0.f;
  }

  float* H0buf[2] = { p.H0, p.H0 + kB * kH };
  float* H1buf[2] = { p.H1, p.H1 + kB * kH };
  float c0[4] = {0.f, 0.f, 0.f, 0.f};
  float c1[4] = {0.f, 0.f, 0.f, 0.f};

  unsigned* domSlots = p.bar + bh * 2048;
  unsigned* domGen   = p.bar + 4096 + bh * 16;
  const bool leader  = (cgi == 0);
  unsigned rnd = 0;

  sync_group(domSlots, domGen, cgi, 128, leader, rnd); rnd++;  // W/zeros ready

  // Phase: C chunks of 128 k. u from global into registers (2-chunk-ahead
  // static dbuf uA/uB); W from LDS (read-only). No block syncs, no LDS u.
  auto runPhase = [&](int C, auto&& src, const float* __restrict__ wl,
                      int wstride, const float* __restrict__ bl,
                      float* cs, float* __restrict__ hout) {
    float acc[16];
    #pragma unroll
    for (int r2 = 0; r2 < 16; ++r2) acc[r2] = 0.f;

    auto compute = [&](int c, const float4 u0, const float4 u1) {
      #pragma unroll
      for (int r2 = 0; r2 < 16; ++r2) {
        const float* wr = wl + r2 * wstride + c * 128 + kt * 8;
        const float4 w0q = *(const float4*)(wr);
        const float4 w1q = *(const float4*)(wr + 4);
        float a = acc[r2];
        a = fmaf(w0q.x, u0.x, a); a = fmaf(w0q.y, u0.y, a);
        a = fmaf(w0q.z, u0.z, a); a = fmaf(w0q.w, u0.w, a);
        a = fmaf(w1q.x, u1.x, a); a = fmaf(w1q.y, u1.y, a);
        a = fmaf(w1q.z, u1.z, a); a = fmaf(w1q.w, u1.w, a);
        acc[r2] = a;
      }
    };

    // uA = even chunks, uB = odd chunks (static names -> no spills);
    // loads are this thread's OWN consumption: floats [8kt, 8kt+8) of chunk.
    float4 uA0 = *(const float4*)src(0, bme, 2 * kt);
    float4 uA1 = *(const float4*)src(0, bme, 2 * kt + 1);
    float4 uB0, uB1;
    if (C > 1) {
      uB0 = *(const float4*)src(1, bme, 2 * kt);
      uB1 = *(const float4*)src(1, bme, 2 * kt + 1);
    }

    for (int cc = 0; cc < C; cc += 2) {
      { // even chunk c = cc (uA)
        const int c = cc;
        const float4 d0 = uA0, d1 = uA1;
        if (c + 2 < C) {                 // prefetch c+2: ~2-chunk latency win
          uA0 = *(const float4*)src(c + 2, bme, 2 * kt);
          uA1 = *(const float4*)src(c + 2, bme, 2 * kt + 1);
        }
        compute(c, d0, d1);
      }
      if (cc + 1 < C) { // odd chunk c = cc+1 (uB)
        const int c = cc + 1;
        const float4 d0 = uB0, d1 = uB1;
        if (c + 2 < C) {
          uB0 = *(const float4*)src(c + 2, bme, 2 * kt);
          uB1 = *(const float4*)src(c + 2, bme, 2 * kt + 1);
        }
        compute(c, d0, d1);
      }
    }

    // in-wave k-reduce over kt (lane bits 0..3) — exact, deterministic
    #pragma unroll
    for (int r2 = 0; r2 < 16; ++r2) {
      float v = acc[r2];
      v += __shfl_xor(v, 1, 64);
      v += __shfl_xor(v, 2, 64);
      v += __shfl_xor(v, 4, 64);
      v += __shfl_xor(v, 8, 64);
      acc[r2] = v;
    }
    // thread-local activation (all kt lanes redundantly; bit-identical)
    #pragma unroll
    for (int jl = 0; jl < 4; ++jl) {
      const float fg = sigmoidf_(acc[0 * 4 + jl] + bl[0 * 4 + jl]);
      const float ig = sigmoidf_(acc[1 * 4 + jl] + bl[1 * 4 + jl]);
      const float og = sigmoidf_(acc[2 * 4 + jl] + bl[2 * 4 + jl]);
      const float gg = tanhf(acc[3 * 4 + jl] + bl[3 * 4 + jl]);
      cs[jl] = fg * cs[jl] + ig * gg;
      const float hv = og * tanhf(cs[jl]);
      if (kt == 0) hout[bme * kH + j0 + jl] = hv;
    }
  };

  // ---------- fused sequence: 1 domain barrier per step ----------
  {
    const float* __restrict__ h0prev = H0buf[1];
    auto srcA = [&](int c, int b, int q4) {
      return (c == 0) ? p.x + (b * kS + 0) * kD + q4 * 4
                      : h0prev + b * kH + (c - 1) * 128 + q4 * 4;
    };
    runPhase(5, srcA, wlds0, 644, &blds[0], c0, H0buf[0]);
  }
  sync_group(domSlots, domGen, cgi, 128, leader, rnd); rnd++;

  for (int t = 0; t < kS; ++t) {
    {
      const float* __restrict__ h0cur  = H0buf[t & 1];
      const float* __restrict__ h1prev = H1buf[(t + 1) & 1];
      auto srcB = [&](int c, int b, int q4) {
        return (c < 4) ? h0cur + b * kH + c * 128 + q4 * 4
                       : h1prev + b * kH + (c - 4) * 128 + q4 * 4;
      };
      runPhase(8, srcB, wlds1, 1028, &blds[16], c1, H1buf[t & 1]);
    }
    if (t < kS - 1) {
      const int tn = t + 1;
      const float* __restrict__ h0prev = H0buf[t & 1];
      auto srcA = [&](int c, int b, int q4) {
        return (c == 0) ? p.x + (b * kS + tn) * kD + q4 * 4
                        : h0prev + b * kH + (c - 1) * 128 + q4 * 4;
      };
      runPhase(5, srcA, wlds0, 644, &blds[0], c0, H0buf[(t + 1) & 1]);
    }
    sync_group(domSlots, domGen, cgi, 128, leader, rnd); rnd++;
  }

  // ---------- head: fc1 -> (FULL barrier) -> fc2 -> relu ----------
  const float* h1f = H1buf[(kS - 1) & 1];
  if (tid < 128) {
    const int jl = tid >> 5, bb = tid & 31;
    const int b = bbase + bb;
    const float* __restrict__ wrr = p.fc1w + (j0 + jl) * kH;
    const float* __restrict__ hr = h1f + b * kH;
    float s = p.fc1b[j0 + jl];
    for (int k = 0; k < kH; k += 4) {
      const float4 wv4 = *(const float4*)(wrr + k);
      const float4 hv = *(const float4*)(hr + k);
      s = fmaf(wv4.x, hv.x, s); s = fmaf(wv4.y, hv.y, s);
      s = fmaf(wv4.z, hv.z, s); s = fmaf(wv4.w, hv.w, s);
    }
    p.tmp1[b * kH + j0 + jl] = s;
  }
  // fc2 reads tmp1 across BOTH domains -> one full-grid barrier
  sync_group(p.bar + 4224, p.bar + 8320, bid, 256, bid == 0, 0u);

  if (bid < kOut && tid < kB) {
    const int b = tid;
    const float* __restrict__ wrr = p.fc2w + bid * kH;
    const float* __restrict__ tr = p.tmp1 + b * kH;
    float s = p.fc2b[bid];
    for (int k = 0; k < kH; k += 4) {
      const float4 wv4 = *(const float4*)(wrr + k);
      const float4 tv = *(const float4*)(tr + k);
      s = fmaf(wv4.x, tv.x, s); s = fmaf(wv4.y, tv.y, s);
      s = fmaf(wv4.z, tv.z, s); s = fmaf(wv4.w, tv.w, s);
    }
    p.out[b * kOut + bid] = fmaxf(s, 0.f);
  }
}

extern "C" void kernel_launch(void* const* d_in, const int* in_sizes, int n_in,
                              void* d_out, int out_size, void* d_ws, size_t ws_size,
                              hipStream_t stream) {
  (void)in_sizes; (void)n_in; (void)out_size; (void)ws_size;
  Params p;
  p.x = (const float*)d_in[0];
  p.w0[0] = (const float*)d_in[1];  p.b0[0] = (const float*)d_in[2];
  p.w0[1] = (const float*)d_in[3];  p.b0[1] = (const float*)d_in[4];
  p.w0[2] = (const float*)d_in[5];  p.b0[2] = (const float*)d_in[6];
  p.w0[3] = (const float*)d_in[7];  p.b0[3] = (const float*)d_in[8];
  p.w1[0] = (const float*)d_in[9];  p.b1[0] = (const float*)d_in[10];
  p.w1[1] = (const float*)d_in[11]; p.b1[1] = (const float*)d_in[12];
  p.w1[2] = (const float*)d_in[13]; p.b1[2] = (const float*)d_in[14];
  p.w1[3] = (const float*)d_in[15]; p.b1[3] = (const float*)d_in[16];
  p.fc1w = (const float*)d_in[17];  p.fc1b = (const float*)d_in[18];
  p.fc2w = (const float*)d_in[19];  p.fc2b = (const float*)d_in[20];

  float* ws = (float*)d_ws;
  p.H0   = ws;                       // 2 * 64*512
  p.H1   = ws + 2 * kB * kH;         // 2 * 64*512
  p.tmp1 = ws + 4 * kB * kH;         // 64*512
  p.bar  = (unsigned*)((char*)d_ws + kBarOffBytes);
  p.out  = (float*)d_out;

  // barrier state must start at 0 (ws is poisoned 0xAA before every launch)
  hipMemsetAsync((char*)d_ws + kBarOffBytes, 0, 36864, stream);

  void* args[] = { &p };
  hipLaunchCooperativeKernel(reinterpret_cast<const void*>(&lstm_persistent),
                             dim3(kBlocks), dim3(kThreads), args, 0, stream);
}

// Round 10
// 14425.958 us; speedup vs baseline: 1.3068x; 1.0322x over previous
//
#include <hip/hip_runtime.h>
#include <cmath>

constexpr int kB = 64, kS = 512, kD = 128, kH = 512, kOut = 24;
constexpr int kBlocks = 256, kThreads = 512;   // grid<=256: proven coop-launchable
constexpr size_t kBarOffBytes = (size_t)5 * kB * kH * 4;   // after H0,H1,tmp1

struct Params {
  const float* x;
  const float* w0[4]; const float* b0[4];   // f,i,o,g  [512,640] / [512]
  const float* w1[4]; const float* b1[4];   // f,i,o,g  [512,1024] / [512]
  const float* fc1w; const float* fc1b;
  const float* fc2w; const float* fc2b;
  float* H0;    // 2 buffers [64][512]
  float* H1;    // 2 buffers [64][512]
  float* tmp1;  // [64][512]
  unsigned* bar; // word layout: dom slots [0,4096), dom gen @4096+d*16,
                 //              full slots [4224,8320), full gen @8320
  float* out;   // [64][24]
};

__device__ __forceinline__ float sigmoidf_(float v) {
  return 1.0f / (1.0f + expf(-v));
}

// Store-based group barrier (parallel slot stores, no RMW serialization;
// round-4 verified). Leader polls n slots with n lanes + __syncthreads_and.
__device__ __forceinline__ void sync_group(unsigned* slots, unsigned* gen,
                                           int myIdx, int n, bool leader,
                                           unsigned r) {
  const int tid = threadIdx.x;
  __syncthreads();
  if (leader) {
    if (tid == 0) {
      __threadfence();
      __hip_atomic_store(slots + myIdx * 16, r + 1, __ATOMIC_RELAXED,
                         __HIP_MEMORY_SCOPE_AGENT);
    }
    unsigned* ps = slots + (tid < n ? tid : 0) * 16;
    for (;;) {
      unsigned v = __hip_atomic_load(ps, __ATOMIC_RELAXED,
                                     __HIP_MEMORY_SCOPE_AGENT);
      if (__syncthreads_and((tid < n) ? (int)(v > r) : 1)) break;
      __builtin_amdgcn_s_sleep(1);
    }
    __threadfence();
    if (tid == 0)
      __hip_atomic_store(gen, r + 1, __ATOMIC_RELAXED,
                         __HIP_MEMORY_SCOPE_AGENT);
    __syncthreads();
  } else {
    if (tid == 0) {
      __threadfence();
      __hip_atomic_store(slots + myIdx * 16, r + 1, __ATOMIC_RELAXED,
                         __HIP_MEMORY_SCOPE_AGENT);
      while (__hip_atomic_load(gen, __ATOMIC_RELAXED,
                               __HIP_MEMORY_SCOPE_AGENT) <= r)
        __builtin_amdgcn_s_sleep(1);
      __threadfence();
    }
    __syncthreads();
  }
}

// ROUND-10: round-9 (passed, 14.9ms) with ONE change: the k-slice permutation.
// Round-9 counters: SQ_LDS_BANK_CONFLICT=1.745e9 = 5.5us/step of stall, fully
// attributed to W LDS reads at float offset kt*8 (16 lanes -> banks
// {0-3,8-11,16-19,24-27} x4 = 4-way conflict on every W read instruction).
// Since the kt->k-indices assignment is arbitrary (butterfly sums all k),
// re-permute: lane kt now owns k floats [4kt,4kt+4) u [64+4kt,64+4kt+4).
//   - W read addrs per instr: float offset 4kt -> banks 4kt mod 32 = all 32
//     banks exactly 2-deep -> conflict-FREE (2-way aliasing is free, m136).
//   - u global loads use the same mapping: instr1 = 16 lanes x 16B contiguous
//     256B (better coalescing than round-9's half-sparse 512B).
//   - butterfly/activation/barriers byte-identical to round 9 (pure
//     re-permutation of a summed index set -> correctness preserved).
__global__ void __launch_bounds__(kThreads, 2)
lstm_persistent(Params p) {
  __shared__ float wlds0[16 * 644];    // 41.2 KB  w0 slice (row stride 644)
  __shared__ float wlds1[16 * 1028];   // 65.8 KB  w1 slice (row stride 1028)
  __shared__ float blds[32];           // biases [layer][16 rows]

  const int tid = threadIdx.x;
  const int bid = blockIdx.x;
  const int cgi = bid >> 1;
  const int bh  = bid & 1;
  const int j0  = cgi * 4;
  const int bbase = bh * 32;

  const int wv = tid >> 6;
  const int l  = tid & 63;
  const int kt = l & 15;               // k-slice: [4kt,4kt+4) u [64+4kt,+4)
  const int bi = l >> 4;               // wave-local batch 0..3
  const int bme = bbase + wv * 4 + bi; // this thread's batch

  // one-time: W slices -> LDS (row r = gate*4 + col, padded strides)
  for (int idx = tid; idx < 16 * 160; idx += kThreads) {   // w0: 16 x 160 f4
    const int row = idx / 160;
    const int k4  = idx - row * 160;
    *(float4*)(wlds0 + row * 644 + k4 * 4) =
        *(const float4*)(p.w0[row >> 2] + (j0 + (row & 3)) * 640 + k4 * 4);
  }
  for (int idx = tid; idx < 16 * 256; idx += kThreads) {   // w1: 16 x 256 f4
    const int row = idx >> 8;
    const int k4  = idx & 255;
    *(float4*)(wlds1 + row * 1028 + k4 * 4) =
        *(const float4*)(p.w1[row >> 2] + (j0 + (row & 3)) * 1024 + k4 * 4);
  }
  if (tid < 16)       blds[tid] = p.b0[tid >> 2][j0 + (tid & 3)];
  else if (tid < 32)  blds[tid] = p.b1[(tid - 16) >> 2][j0 + (tid & 3)];

  // zero-init buffers read at t=0 (buffer index 1)
  if (tid < 128) {
    const int jl = tid >> 5, bb = tid & 31;
    const int b = bbase + bb;
    p.H0[kB * kH + b * kH + j0 + jl] = 0.f;
    p.H1[kB * kH + b * kH + j0 + jl] = 0.f;
  }

  float* H0buf[2] = { p.H0, p.H0 + kB * kH };
  float* H1buf[2] = { p.H1, p.H1 + kB * kH };
  float c0[4] = {0.f, 0.f, 0.f, 0.f};
  float c1[4] = {0.f, 0.f, 0.f, 0.f};

  unsigned* domSlots = p.bar + bh * 2048;
  unsigned* domGen   = p.bar + 4096 + bh * 16;
  const bool leader  = (cgi == 0);
  unsigned rnd = 0;

  sync_group(domSlots, domGen, cgi, 128, leader, rnd); rnd++;  // W/zeros ready

  // Phase: C chunks of 128 k. u from global into registers (2-chunk-ahead
  // static dbuf uA/uB); W from LDS (read-only, conflict-free addressing).
  auto runPhase = [&](int C, auto&& src, const float* __restrict__ wl,
                      int wstride, const float* __restrict__ bl,
                      float* cs, float* __restrict__ hout) {
    float acc[16];
    #pragma unroll
    for (int r2 = 0; r2 < 16; ++r2) acc[r2] = 0.f;

    auto compute = [&](int c, const float4 u0, const float4 u1) {
      #pragma unroll
      for (int r2 = 0; r2 < 16; ++r2) {
        const float* wr = wl + r2 * wstride + c * 128;
        const float4 w0q = *(const float4*)(wr + kt * 4);        // banks 4kt
        const float4 w1q = *(const float4*)(wr + 64 + kt * 4);   // banks 4kt
        float a = acc[r2];
        a = fmaf(w0q.x, u0.x, a); a = fmaf(w0q.y, u0.y, a);
        a = fmaf(w0q.z, u0.z, a); a = fmaf(w0q.w, u0.w, a);
        a = fmaf(w1q.x, u1.x, a); a = fmaf(w1q.y, u1.y, a);
        a = fmaf(w1q.z, u1.z, a); a = fmaf(w1q.w, u1.w, a);
        acc[r2] = a;
      }
    };

    // uA = even chunks, uB = odd chunks (static names -> no spills);
    // loads are this thread's OWN k-slice: f4 quads kt and 16+kt of the chunk.
    float4 uA0 = *(const float4*)src(0, bme, kt);
    float4 uA1 = *(const float4*)src(0, bme, 16 + kt);
    float4 uB0, uB1;
    if (C > 1) {
      uB0 = *(const float4*)src(1, bme, kt);
      uB1 = *(const float4*)src(1, bme, 16 + kt);
    }

    for (int cc = 0; cc < C; cc += 2) {
      { // even chunk c = cc (uA)
        const int c = cc;
        const float4 d0 = uA0, d1 = uA1;
        if (c + 2 < C) {                 // prefetch c+2: ~2-chunk latency win
          uA0 = *(const float4*)src(c + 2, bme, kt);
          uA1 = *(const float4*)src(c + 2, bme, 16 + kt);
        }
        compute(c, d0, d1);
      }
      if (cc + 1 < C) { // odd chunk c = cc+1 (uB)
        const int c = cc + 1;
        const float4 d0 = uB0, d1 = uB1;
        if (c + 2 < C) {
          uB0 = *(const float4*)src(c + 2, bme, kt);
          uB1 = *(const float4*)src(c + 2, bme, 16 + kt);
        }
        compute(c, d0, d1);
      }
    }

    // in-wave k-reduce over kt (lane bits 0..3) — exact, deterministic
    #pragma unroll
    for (int r2 = 0; r2 < 16; ++r2) {
      float v = acc[r2];
      v += __shfl_xor(v, 1, 64);
      v += __shfl_xor(v, 2, 64);
      v += __shfl_xor(v, 4, 64);
      v += __shfl_xor(v, 8, 64);
      acc[r2] = v;
    }
    // thread-local activation (all kt lanes redundantly; bit-identical)
    #pragma unroll
    for (int jl = 0; jl < 4; ++jl) {
      const float fg = sigmoidf_(acc[0 * 4 + jl] + bl[0 * 4 + jl]);
      const float ig = sigmoidf_(acc[1 * 4 + jl] + bl[1 * 4 + jl]);
      const float og = sigmoidf_(acc[2 * 4 + jl] + bl[2 * 4 + jl]);
      const float gg = tanhf(acc[3 * 4 + jl] + bl[3 * 4 + jl]);
      cs[jl] = fg * cs[jl] + ig * gg;
      const float hv = og * tanhf(cs[jl]);
      if (kt == 0) hout[bme * kH + j0 + jl] = hv;
    }
  };

  // ---------- fused sequence: 1 domain barrier per step ----------
  {
    const float* __restrict__ h0prev = H0buf[1];
    auto srcA = [&](int c, int b, int q4) {
      return (c == 0) ? p.x + (b * kS + 0) * kD + q4 * 4
                      : h0prev + b * kH + (c - 1) * 128 + q4 * 4;
    };
    runPhase(5, srcA, wlds0, 644, &blds[0], c0, H0buf[0]);
  }
  sync_group(domSlots, domGen, cgi, 128, leader, rnd); rnd++;

  for (int t = 0; t < kS; ++t) {
    {
      const float* __restrict__ h0cur  = H0buf[t & 1];
      const float* __restrict__ h1prev = H1buf[(t + 1) & 1];
      auto srcB = [&](int c, int b, int q4) {
        return (c < 4) ? h0cur + b * kH + c * 128 + q4 * 4
                       : h1prev + b * kH + (c - 4) * 128 + q4 * 4;
      };
      runPhase(8, srcB, wlds1, 1028, &blds[16], c1, H1buf[t & 1]);
    }
    if (t < kS - 1) {
      const int tn = t + 1;
      const float* __restrict__ h0prev = H0buf[t & 1];
      auto srcA = [&](int c, int b, int q4) {
        return (c == 0) ? p.x + (b * kS + tn) * kD + q4 * 4
                        : h0prev + b * kH + (c - 1) * 128 + q4 * 4;
      };
      runPhase(5, srcA, wlds0, 644, &blds[0], c0, H0buf[(t + 1) & 1]);
    }
    sync_group(domSlots, domGen, cgi, 128, leader, rnd); rnd++;
  }

  // ---------- head: fc1 -> (FULL barrier) -> fc2 -> relu ----------
  const float* h1f = H1buf[(kS - 1) & 1];
  if (tid < 128) {
    const int jl = tid >> 5, bb = tid & 31;
    const int b = bbase + bb;
    const float* __restrict__ wrr = p.fc1w + (j0 + jl) * kH;
    const float* __restrict__ hr = h1f + b * kH;
    float s = p.fc1b[j0 + jl];
    for (int k = 0; k < kH; k += 4) {
      const float4 wv4 = *(const float4*)(wrr + k);
      const float4 hv = *(const float4*)(hr + k);
      s = fmaf(wv4.x, hv.x, s); s = fmaf(wv4.y, hv.y, s);
      s = fmaf(wv4.z, hv.z, s); s = fmaf(wv4.w, hv.w, s);
    }
    p.tmp1[b * kH + j0 + jl] = s;
  }
  // fc2 reads tmp1 across BOTH domains -> one full-grid barrier
  sync_group(p.bar + 4224, p.bar + 8320, bid, 256, bid == 0, 0u);

  if (bid < kOut && tid < kB) {
    const int b = tid;
    const float* __restrict__ wrr = p.fc2w + bid * kH;
    const float* __restrict__ tr = p.tmp1 + b * kH;
    float s = p.fc2b[bid];
    for (int k = 0; k < kH; k += 4) {
      const float4 wv4 = *(const float4*)(wrr + k);
      const float4 tv = *(const float4*)(tr + k);
      s = fmaf(wv4.x, tv.x, s); s = fmaf(wv4.y, tv.y, s);
      s = fmaf(wv4.z, tv.z, s); s = fmaf(wv4.w, tv.w, s);
    }
    p.out[b * kOut + bid] = fmaxf(s, 0.f);
  }
}

extern "C" void kernel_launch(void* const* d_in, const int* in_sizes, int n_in,
                              void* d_out, int out_size, void* d_ws, size_t ws_size,
                              hipStream_t stream) {
  (void)in_sizes; (void)n_in; (void)out_size; (void)ws_size;
  Params p;
  p.x = (const float*)d_in[0];
  p.w0[0] = (const float*)d_in[1];  p.b0[0] = (const float*)d_in[2];
  p.w0[1] = (const float*)d_in[3];  p.b0[1] = (const float*)d_in[4];
  p.w0[2] = (const float*)d_in[5];  p.b0[2] = (const float*)d_in[6];
  p.w0[3] = (const float*)d_in[7];  p.b0[3] = (const float*)d_in[8];
  p.w1[0] = (const float*)d_in[9];  p.b1[0] = (const float*)d_in[10];
  p.w1[1] = (const float*)d_in[11]; p.b1[1] = (const float*)d_in[12];
  p.w1[2] = (const float*)d_in[13]; p.b1[2] = (const float*)d_in[14];
  p.w1[3] = (const float*)d_in[15]; p.b1[3] = (const float*)d_in[16];
  p.fc1w = (const float*)d_in[17];  p.fc1b = (const float*)d_in[18];
  p.fc2w = (const float*)d_in[19];  p.fc2b = (const float*)d_in[20];

  float* ws = (float*)d_ws;
  p.H0   = ws;                       // 2 * 64*512
  p.H1   = ws + 2 * kB * kH;         // 2 * 64*512
  p.tmp1 = ws + 4 * kB * kH;         // 64*512
  p.bar  = (unsigned*)((char*)d_ws + kBarOffBytes);
  p.out  = (float*)d_out;

  // barrier state must start at 0 (ws is poisoned 0xAA before every launch)
  hipMemsetAsync((char*)d_ws + kBarOffBytes, 0, 36864, stream);

  void* args[] = { &p };
  hipLaunchCooperativeKernel(reinterpret_cast<const void*>(&lstm_persistent),
                             dim3(kBlocks), dim3(kThreads), args, 0, stream);
}

// Round 11
// 12422.848 us; speedup vs baseline: 1.5175x; 1.1612x over previous
//
#include <hip/hip_runtime.h>
#include <cmath>

constexpr int kB = 64, kS = 512, kD = 128, kH = 512, kOut = 24;
constexpr int kBlocks = 256, kThreads = 512;   // grid<=256: proven coop-launchable
constexpr size_t kBarOffBytes = (size_t)5 * kB * kH * 4;   // after H0,H1,tmp1

struct Params {
  const float* x;
  const float* w0[4]; const float* b0[4];   // f,i,o,g  [512,640] / [512]
  const float* w1[4]; const float* b1[4];   // f,i,o,g  [512,1024] / [512]
  const float* fc1w; const float* fc1b;
  const float* fc2w; const float* fc2b;
  float* H0;    // 2 buffers [64][512]
  float* H1;    // 2 buffers [64][512]
  float* tmp1;  // [64][512]
  unsigned* bar; // word layout: dom slots [0,4096), dom gen @4096+d*16,
                 //              full slots [4224,8320), full gen @8320
  float* out;   // [64][24]
};

__device__ __forceinline__ float sigmoidf_(float v) {
  return 1.0f / (1.0f + expf(-v));
}

// Store-based group barrier (parallel slot stores, no RMW serialization;
// round-4 verified). Leader polls n slots with n lanes + __syncthreads_and.
__device__ __forceinline__ void sync_group(unsigned* slots, unsigned* gen,
                                           int myIdx, int n, bool leader,
                                           unsigned r) {
  const int tid = threadIdx.x;
  __syncthreads();
  if (leader) {
    if (tid == 0) {
      __threadfence();
      __hip_atomic_store(slots + myIdx * 16, r + 1, __ATOMIC_RELAXED,
                         __HIP_MEMORY_SCOPE_AGENT);
    }
    unsigned* ps = slots + (tid < n ? tid : 0) * 16;
    for (;;) {
      unsigned v = __hip_atomic_load(ps, __ATOMIC_RELAXED,
                                     __HIP_MEMORY_SCOPE_AGENT);
      if (__syncthreads_and((tid < n) ? (int)(v > r) : 1)) break;
      __builtin_amdgcn_s_sleep(1);
    }
    __threadfence();
    if (tid == 0)
      __hip_atomic_store(gen, r + 1, __ATOMIC_RELAXED,
                         __HIP_MEMORY_SCOPE_AGENT);
    __syncthreads();
  } else {
    if (tid == 0) {
      __threadfence();
      __hip_atomic_store(slots + myIdx * 16, r + 1, __ATOMIC_RELAXED,
                         __HIP_MEMORY_SCOPE_AGENT);
      while (__hip_atomic_load(gen, __ATOMIC_RELAXED,
                               __HIP_MEMORY_SCOPE_AGENT) <= r)
        __builtin_amdgcn_s_sleep(1);
      __threadfence();
    }
    __syncthreads();
  }
}

// ROUND-11: round-10 with the lane tile TRANSPOSED to minimize DS instrs.
// Round-10 evidence: conflicts==0 yet time flat -> DS cost is the INHERENT
// ~8 bank-rounds per ds_read_b128 x instruction count (3328/CU/step = ~16.6us
// of DS-pipe occupancy), driven by 4-way W-read redundancy across bi lanes.
// New lane map: l = kt*4 + ci  (kt = l>>2 k-slice, ci = l&3 column).
//   Thread: col j0+ci, ALL 4 gates, ALL 4 wave batches, k-slice
//   [4kt,4kt+4) u [64+4kt,+4)  ->  acc[4 gates][4 batches] (16, same FMAs).
//   - W per chunk: 8 ds_read_b128, ALL 64 lanes distinct (minimum possible;
//     was 32 with 4-way broadcast). Banks: addr/4 mod 32 = 16g+4(ci+kt) ->
//     每 4-bank group serves exactly 8 lanes = inherent rounds, 0 excess.
//   - u per chunk: 8 VMEM f4 (4x redundant across ci; same-addr lanes merge,
//     256B contiguous per instr, L1/L2-served -- VMEM pipe has slack).
//   - butterfly over kt = lane bits 2..5: masks 4,8,16,32.
//   - activation thread-local (4 gates of one col); cs[4] per batch.
__global__ void __launch_bounds__(kThreads, 2)
lstm_persistent(Params p) {
  __shared__ float wlds0[16 * 644];    // 41.2 KB  w0 slice (row stride 644)
  __shared__ float wlds1[16 * 1028];   // 65.8 KB  w1 slice (row stride 1028)
  __shared__ float blds[32];           // biases [layer][16 rows]

  const int tid = threadIdx.x;
  const int bid = blockIdx.x;
  const int cgi = bid >> 1;
  const int bh  = bid & 1;
  const int j0  = cgi * 4;
  const int bbase = bh * 32;

  const int wv = tid >> 6;
  const int l  = tid & 63;
  const int kt = l >> 2;               // k-slice: [4kt,4kt+4) u [64+4kt,+4)
  const int ci = l & 3;                // column j0+ci
  const int bw0 = bbase + wv * 4;      // wave's first batch

  // one-time: W slices -> LDS (row r = gate*4 + col, padded strides)
  for (int idx = tid; idx < 16 * 160; idx += kThreads) {   // w0: 16 x 160 f4
    const int row = idx / 160;
    const int k4  = idx - row * 160;
    *(float4*)(wlds0 + row * 644 + k4 * 4) =
        *(const float4*)(p.w0[row >> 2] + (j0 + (row & 3)) * 640 + k4 * 4);
  }
  for (int idx = tid; idx < 16 * 256; idx += kThreads) {   // w1: 16 x 256 f4
    const int row = idx >> 8;
    const int k4  = idx & 255;
    *(float4*)(wlds1 + row * 1028 + k4 * 4) =
        *(const float4*)(p.w1[row >> 2] + (j0 + (row & 3)) * 1024 + k4 * 4);
  }
  if (tid < 16)       blds[tid] = p.b0[tid >> 2][j0 + (tid & 3)];
  else if (tid < 32)  blds[tid] = p.b1[(tid - 16) >> 2][j0 + (tid & 3)];

  // zero-init buffers read at t=0 (buffer index 1)
  if (tid < 128) {
    const int jl = tid >> 5, bb = tid & 31;
    const int b = bbase + bb;
    p.H0[kB * kH + b * kH + j0 + jl] = 0.f;
    p.H1[kB * kH + b * kH + j0 + jl] = 0.f;
  }

  float* H0buf[2] = { p.H0, p.H0 + kB * kH };
  float* H1buf[2] = { p.H1, p.H1 + kB * kH };
  float c0[4] = {0.f, 0.f, 0.f, 0.f};   // cell state per wave-batch (col ci)
  float c1[4] = {0.f, 0.f, 0.f, 0.f};

  unsigned* domSlots = p.bar + bh * 2048;
  unsigned* domGen   = p.bar + 4096 + bh * 16;
  const bool leader  = (cgi == 0);
  unsigned rnd = 0;

  sync_group(domSlots, domGen, cgi, 128, leader, rnd); rnd++;  // W/zeros ready

  // Phase: C chunks of 128 k. u from global into registers (2-chunk-ahead
  // static dbuf uA/uB, unrolled-constant indexing only); W from LDS.
  auto runPhase = [&](int C, auto&& src, const float* __restrict__ wl,
                      int wstride, const float* __restrict__ bl,
                      float* cs, float* __restrict__ hout) {
    float acc[4][4];
    #pragma unroll
    for (int g = 0; g < 4; ++g)
      #pragma unroll
      for (int bb = 0; bb < 4; ++bb) acc[g][bb] = 0.f;

    // compute: u8[q] = quad for (batch q>>1, half q&1)
    auto compute = [&](int c, const float4* u8) {
      #pragma unroll
      for (int half = 0; half < 2; ++half) {
        float4 wq[4];
        #pragma unroll
        for (int g = 0; g < 4; ++g)
          wq[g] = *(const float4*)(wl + (g * 4 + ci) * wstride + c * 128 +
                                   half * 64 + kt * 4);
        #pragma unroll
        for (int g = 0; g < 4; ++g)
          #pragma unroll
          for (int bb = 0; bb < 4; ++bb) {
            const float4 u4 = u8[bb * 2 + half];
            float a = acc[g][bb];
            a = fmaf(wq[g].x, u4.x, a); a = fmaf(wq[g].y, u4.y, a);
            a = fmaf(wq[g].z, u4.z, a); a = fmaf(wq[g].w, u4.w, a);
            acc[g][bb] = a;
          }
      }
    };

    // uA = even chunks, uB = odd chunks; q4 index = half*16 + kt
    float4 uA[8], uB[8];
    #pragma unroll
    for (int q = 0; q < 8; ++q)
      uA[q] = *(const float4*)src(0, bw0 + (q >> 1), (q & 1) * 16 + kt);
    if (C > 1) {
      #pragma unroll
      for (int q = 0; q < 8; ++q)
        uB[q] = *(const float4*)src(1, bw0 + (q >> 1), (q & 1) * 16 + kt);
    }

    for (int cc = 0; cc < C; cc += 2) {
      { // even chunk c = cc (uA)
        const int c = cc;
        float4 d[8];
        #pragma unroll
        for (int q = 0; q < 8; ++q) d[q] = uA[q];
        if (c + 2 < C) {
          #pragma unroll
          for (int q = 0; q < 8; ++q)
            uA[q] = *(const float4*)src(c + 2, bw0 + (q >> 1),
                                        (q & 1) * 16 + kt);
        }
        compute(c, d);
      }
      if (cc + 1 < C) { // odd chunk c = cc+1 (uB)
        const int c = cc + 1;
        float4 d[8];
        #pragma unroll
        for (int q = 0; q < 8; ++q) d[q] = uB[q];
        if (c + 2 < C) {
          #pragma unroll
          for (int q = 0; q < 8; ++q)
            uB[q] = *(const float4*)src(c + 2, bw0 + (q >> 1),
                                        (q & 1) * 16 + kt);
        }
        compute(c, d);
      }
    }

    // in-wave k-reduce over kt (lane bits 2..5) — exact, deterministic
    #pragma unroll
    for (int g = 0; g < 4; ++g)
      #pragma unroll
      for (int bb = 0; bb < 4; ++bb) {
        float v = acc[g][bb];
        v += __shfl_xor(v, 4, 64);
        v += __shfl_xor(v, 8, 64);
        v += __shfl_xor(v, 16, 64);
        v += __shfl_xor(v, 32, 64);
        acc[g][bb] = v;
      }
    // thread-local activation (all kt lanes redundantly; bit-identical)
    #pragma unroll
    for (int bb = 0; bb < 4; ++bb) {
      const float fg = sigmoidf_(acc[0][bb] + bl[0 * 4 + ci]);
      const float ig = sigmoidf_(acc[1][bb] + bl[1 * 4 + ci]);
      const float og = sigmoidf_(acc[2][bb] + bl[2 * 4 + ci]);
      const float gg = tanhf(acc[3][bb] + bl[3 * 4 + ci]);
      cs[bb] = fg * cs[bb] + ig * gg;
      const float hv = og * tanhf(cs[bb]);
      if (l < 4) hout[(bw0 + bb) * kH + j0 + ci] = hv;   // kt==0 lanes write
    }
  };

  // ---------- fused sequence: 1 domain barrier per step ----------
  {
    const float* __restrict__ h0prev = H0buf[1];
    auto srcA = [&](int c, int b, int q4) {
      return (c == 0) ? p.x + (b * kS + 0) * kD + q4 * 4
                      : h0prev + b * kH + (c - 1) * 128 + q4 * 4;
    };
    runPhase(5, srcA, wlds0, 644, &blds[0], c0, H0buf[0]);
  }
  sync_group(domSlots, domGen, cgi, 128, leader, rnd); rnd++;

  for (int t = 0; t < kS; ++t) {
    {
      const float* __restrict__ h0cur  = H0buf[t & 1];
      const float* __restrict__ h1prev = H1buf[(t + 1) & 1];
      auto srcB = [&](int c, int b, int q4) {
        return (c < 4) ? h0cur + b * kH + c * 128 + q4 * 4
                       : h1prev + b * kH + (c - 4) * 128 + q4 * 4;
      };
      runPhase(8, srcB, wlds1, 1028, &blds[16], c1, H1buf[t & 1]);
    }
    if (t < kS - 1) {
      const int tn = t + 1;
      const float* __restrict__ h0prev = H0buf[t & 1];
      auto srcA = [&](int c, int b, int q4) {
        return (c == 0) ? p.x + (b * kS + tn) * kD + q4 * 4
                        : h0prev + b * kH + (c - 1) * 128 + q4 * 4;
      };
      runPhase(5, srcA, wlds0, 644, &blds[0], c0, H0buf[(t + 1) & 1]);
    }
    sync_group(domSlots, domGen, cgi, 128, leader, rnd); rnd++;
  }

  // ---------- head: fc1 -> (FULL barrier) -> fc2 -> relu ----------
  const float* h1f = H1buf[(kS - 1) & 1];
  if (tid < 128) {
    const int jl = tid >> 5, bb = tid & 31;
    const int b = bbase + bb;
    const float* __restrict__ wrr = p.fc1w + (j0 + jl) * kH;
    const float* __restrict__ hr = h1f + b * kH;
    float s = p.fc1b[j0 + jl];
    for (int k = 0; k < kH; k += 4) {
      const float4 wv4 = *(const float4*)(wrr + k);
      const float4 hv = *(const float4*)(hr + k);
      s = fmaf(wv4.x, hv.x, s); s = fmaf(wv4.y, hv.y, s);
      s = fmaf(wv4.z, hv.z, s); s = fmaf(wv4.w, hv.w, s);
    }
    p.tmp1[b * kH + j0 + jl] = s;
  }
  // fc2 reads tmp1 across BOTH domains -> one full-grid barrier
  sync_group(p.bar + 4224, p.bar + 8320, bid, 256, bid == 0, 0u);

  if (bid < kOut && tid < kB) {
    const int b = tid;
    const float* __restrict__ wrr = p.fc2w + bid * kH;
    const float* __restrict__ tr = p.tmp1 + b * kH;
    float s = p.fc2b[bid];
    for (int k = 0; k < kH; k += 4) {
      const float4 wv4 = *(const float4*)(wrr + k);
      const float4 tv = *(const float4*)(tr + k);
      s = fmaf(wv4.x, tv.x, s); s = fmaf(wv4.y, tv.y, s);
      s = fmaf(wv4.z, tv.z, s); s = fmaf(wv4.w, tv.w, s);
    }
    p.out[b * kOut + bid] = fmaxf(s, 0.f);
  }
}

extern "C" void kernel_launch(void* const* d_in, const int* in_sizes, int n_in,
                              void* d_out, int out_size, void* d_ws, size_t ws_size,
                              hipStream_t stream) {
  (void)in_sizes; (void)n_in; (void)out_size; (void)ws_size;
  Params p;
  p.x = (const float*)d_in[0];
  p.w0[0] = (const float*)d_in[1];  p.b0[0] = (const float*)d_in[2];
  p.w0[1] = (const float*)d_in[3];  p.b0[1] = (const float*)d_in[4];
  p.w0[2] = (const float*)d_in[5];  p.b0[2] = (const float*)d_in[6];
  p.w0[3] = (const float*)d_in[7];  p.b0[3] = (const float*)d_in[8];
  p.w1[0] = (const float*)d_in[9];  p.b1[0] = (const float*)d_in[10];
  p.w1[1] = (const float*)d_in[11]; p.b1[1] = (const float*)d_in[12];
  p.w1[2] = (const float*)d_in[13]; p.b1[2] = (const float*)d_in[14];
  p.w1[3] = (const float*)d_in[15]; p.b1[3] = (const float*)d_in[16];
  p.fc1w = (const float*)d_in[17];  p.fc1b = (const float*)d_in[18];
  p.fc2w = (const float*)d_in[19];  p.fc2b = (const float*)d_in[20];

  float* ws = (float*)d_ws;
  p.H0   = ws;                       // 2 * 64*512
  p.H1   = ws + 2 * kB * kH;         // 2 * 64*512
  p.tmp1 = ws + 4 * kB * kH;         // 64*512
  p.bar  = (unsigned*)((char*)d_ws + kBarOffBytes);
  p.out  = (float*)d_out;

  // barrier state must start at 0 (ws is poisoned 0xAA before every launch)
  hipMemsetAsync((char*)d_ws + kBarOffBytes, 0, 36864, stream);

  void* args[] = { &p };
  hipLaunchCooperativeKernel(reinterpret_cast<const void*>(&lstm_persistent),
                             dim3(kBlocks), dim3(kThreads), args, 0, stream);
}